// Round 5
// baseline (72.561 us; speedup 1.0000x reference)
//
#include <hip/hip_runtime.h>

// ECT: nh = x @ v -> bin -> histogram over (batch, bin, theta) -> cumsum over bins.
// batch is SORTED: each block owns (batch, theta-slice) exclusively; no global
// atomics, no workspace.
//
// R1: 8x unroll (latency)                 42 -> ~26 us
// R2: 4 thetas/thread (VMEM issue)        ~26 -> ~21 us
// R3: float4 chunk loads + ballot search  ~21 -> ~16 us
// R4: occupancy 16 -> 32 waves/CU: grid 512 (B x 8 slices of 16 thetas),
//     2 blocks/CU. Per-thread work ~50 pairs, kernel = sum of exposed latency
//     phases -> 2x waves halves every exposed term. TG=4 also halves load
//     redundancy (16 distinct chunks per wave-load).
// LDS banking (TT=16): bank = (bin&1)*16 + tl, tl_j=(4tg+j+pl)%16: for fixed j
// each tl hit by 4 lanes, split by random bin parity -> ~2-way avg, 4-way worst.

constexpr int N_PTS    = 200000;
constexpr int T        = 128;   // num_thetas
constexpr int R        = 128;   // resolution
constexpr int B        = 64;    // batch_size
constexpr int SPLIT_T  = 8;     // theta slices per batch
constexpr int TT       = T / SPLIT_T;       // 16 thetas per block
constexpr int NTHREADS = 1024;
constexpr int TG       = 4;                 // theta-groups per block (4 thetas each)
constexpr int PL       = NTHREADS / TG;     // 256 chunk-lanes per block
constexpr int SUBS     = NTHREADS / TT;     // 64 (epilogue partitioning)
constexpr int RCH      = R / SUBS;          // 2 resolution rows per thread in epilogue

__global__ __launch_bounds__(NTHREADS)
void FastEctLayer_73065983639654_kernel(const float* __restrict__ x,
                                        const float* __restrict__ v,
                                        const int*   __restrict__ batch,
                                        float*       __restrict__ out) {
    __shared__ unsigned int hist[R * TT];        // 8 KiB, layout [bin][tl]
    __shared__ unsigned int partial[SUBS * TT];  // 4 KiB
    __shared__ int s_range[2];

    const int tid    = threadIdx.x;
    const int tg     = tid & (TG - 1);           // theta-group 0..3
    const int pl     = tid >> 2;                 // chunk-lane 0..255
    const int bat    = blockIdx.x / SPLIT_T;
    const int theta0 = (blockIdx.x % SPLIT_T) * TT;

    for (int i = tid; i < R * TT; i += NTHREADS) hist[i] = 0u;

    // ---- 64-ary cooperative lower_bound: 200000 -> 3125 -> 49 -> 1 (3 probe
    // rounds, each one dependent global load + ballot). wave 0 -> start, wave 1 -> end.
    const int wave = tid >> 6, lane = tid & 63;
    if (wave < 2) {
        const int val = bat + wave;
        int lo = 0, hi = N_PTS;
        while (lo < hi) {
            const int step = (hi - lo + 63) >> 6;
            const int pos  = lo + lane * step;
            const bool pred = (pos < hi) && (batch[pos] < val);
            const unsigned long long m = __ballot(pred);
            const int k = __popcll(m);
            if (k == 0) {
                hi = lo;
            } else {
                const int nlo = lo + (k - 1) * step + 1;
                hi = min(hi, lo + k * step);
                lo = nlo;
            }
        }
        if (lane == 0) s_range[wave] = lo;
    }

    // this thread's 4 thetas (diagonalized for low-conflict atomics)
    int   tlj[4];
    float vv0[4], vv1[4], vv2[4];
#pragma unroll
    for (int j = 0; j < 4; ++j) {
        const int tl = (4 * tg + j + pl) & (TT - 1);
        tlj[j] = tl;
        vv0[j] = v[0 * T + theta0 + tl];
        vv1[j] = v[1 * T + theta0 + tl];
        vv2[j] = v[2 * T + theta0 + tl];
    }

    __syncthreads();
    const int start = s_range[0];
    const int end   = s_range[1];

    // chunk-of-4 points, 16B-aligned float4 loads. Chunks may cover <=2 points
    // past `end` (next batch) -> predicated out. In-bounds: end==N is 4-aligned
    // with a0; end<N has ~3000 following points.
    const int a0      = start & ~3;
    const int nchunks = (end - a0 + 3) >> 2;
    const float4* __restrict__ X4 = (const float4*)x;
    const int cbase = (a0 >> 2) * 3;             // float4 index of chunk 0

    auto process4 = [&](int pbase, float4 f0, float4 f1, float4 f2) {
        const float px[4] = {f0.x, f0.w, f1.z, f2.y};
        const float py[4] = {f0.y, f1.x, f1.w, f2.z};
        const float pz[4] = {f0.z, f1.y, f2.x, f2.w};
        if (pbase >= start && pbase + 3 < end) {
#pragma unroll
            for (int i = 0; i < 4; ++i) {
#pragma unroll
                for (int j = 0; j < 4; ++j) {
                    const float nh = fmaf(px[i], vv0[j], fmaf(py[i], vv1[j], pz[i] * vv2[j]));
                    int bin = (int)fmaf(nh, 0.5f * (float)R, 0.5f * (float)R);
                    bin = min(max(bin, 0), R - 1);
                    atomicAdd(&hist[bin * TT + tlj[j]], 1u);
                }
            }
        } else {
#pragma unroll
            for (int i = 0; i < 4; ++i) {
                const int p = pbase + i;
                if (p >= start && p < end) {
#pragma unroll
                    for (int j = 0; j < 4; ++j) {
                        const float nh = fmaf(px[i], vv0[j], fmaf(py[i], vv1[j], pz[i] * vv2[j]));
                        int bin = (int)fmaf(nh, 0.5f * (float)R, 0.5f * (float)R);
                        bin = min(max(bin, 0), R - 1);
                        atomicAdd(&hist[bin * TT + tlj[j]], 1u);
                    }
                }
            }
        }
    };

    // main loop: 2 chunks (8 points) in flight, 6 float4 loads per iteration
    int c = pl;
    for (; c + PL < nchunks; c += 2 * PL) {
        const int c2 = c + PL;
        const float4 fa0 = X4[cbase + 3 * c],  fa1 = X4[cbase + 3 * c + 1],  fa2 = X4[cbase + 3 * c + 2];
        const float4 fb0 = X4[cbase + 3 * c2], fb1 = X4[cbase + 3 * c2 + 1], fb2 = X4[cbase + 3 * c2 + 2];
        process4(a0 + 4 * c,  fa0, fa1, fa2);
        process4(a0 + 4 * c2, fb0, fb1, fb2);
    }
    for (; c < nchunks; c += PL) {
        const float4 f0 = X4[cbase + 3 * c], f1 = X4[cbase + 3 * c + 1], f2 = X4[cbase + 3 * c + 2];
        process4(a0 + 4 * c, f0, f1, f2);
    }

    __syncthreads();

    // cumsum over r (two-phase chunked scan), direct store to out[bat][r][theta0+tl]
    const int tl  = tid & (TT - 1);
    const int sub = tid / TT;            // 0..63, owns RCH=2 rows
    const int r0  = sub * RCH;
    unsigned int csum = 0;
#pragma unroll
    for (int r = r0; r < r0 + RCH; ++r) csum += hist[r * TT + tl];
    partial[sub * TT + tl] = csum;
    __syncthreads();

    unsigned int run = 0;
    for (int s = 0; s < sub; ++s) run += partial[s * TT + tl];  // uniform s: LDS broadcast
#pragma unroll
    for (int r = r0; r < r0 + RCH; ++r) {
        run += hist[r * TT + tl];
        out[((size_t)bat * R + r) * T + theta0 + tl] = (float)run;  // counts <= ~3.4K: exact in f32
    }
}

extern "C" void kernel_launch(void* const* d_in, const int* in_sizes, int n_in,
                              void* d_out, int out_size, void* d_ws, size_t ws_size,
                              hipStream_t stream) {
    const float* x     = (const float*)d_in[0];
    const float* v     = (const float*)d_in[1];
    const int*   batch = (const int*)d_in[2];
    float*       out   = (float*)d_out;

    dim3 grid(B * SPLIT_T);   // 512 blocks = 2 per CU -> 32 waves/CU
    dim3 block(NTHREADS);
    hipLaunchKernelGGL(FastEctLayer_73065983639654_kernel, grid, block, 0, stream,
                       x, v, batch, out);
}

// Round 6
// 72.321 us; speedup vs baseline: 1.0033x; 1.0033x over previous
//
#include <hip/hip_runtime.h>

// ECT: nh = x @ v -> bin -> histogram over (batch, bin, theta) -> cumsum over bins.
// batch is SORTED: each block owns (batch, theta-slice) exclusively; no global
// atomics, no workspace.
//
// R1: 8x unroll (latency)                 42 -> ~26 us
// R2: 4 thetas/thread (VMEM issue)        ~26 -> ~21 us
// R3: float4 chunk loads + ballot search  ~21 -> ~16 us
// R4: grid 512 attempt: NEUTRAL - VGPRs > 64 meant 2nd block never resident,
//     and TT=16 banking degraded (4 same-parity lanes/bank).
// R5(this): decisive occupancy test: __launch_bounds__(1024,8) forces VGPR<=64
//     (2 blocks/CU真 resident), dual sub-histogram hist[bin][sub][tl] restores
//     EXACT 2-lanes/bank atomics (4 lanes sharing tl split 2/2 by sub=(pl>>2)&1),
//     v pre-scaled by 64 (+64 bias folded) saves 1 VALU/pair.
// DS wave-instr count is invariant (pairs/64 = 400K); this round tests whether
// the residual ~10us is un-hidden latency (occupancy fixes) or DS throughput.

constexpr int N_PTS    = 200000;
constexpr int T        = 128;   // num_thetas
constexpr int R        = 128;   // resolution
constexpr int B        = 64;    // batch_size
constexpr int SPLIT_T  = 8;     // theta slices per batch
constexpr int TT       = T / SPLIT_T;       // 16 thetas per block
constexpr int NTHREADS = 1024;
constexpr int TG       = 4;                 // theta-groups per block (4 thetas each)
constexpr int PL       = NTHREADS / TG;     // 256 chunk-lanes per block

__global__ __launch_bounds__(NTHREADS, 8)   // 8 waves/SIMD -> VGPR<=64 -> 2 blocks/CU
void FastEctLayer_73065983639654_kernel(const float* __restrict__ x,
                                        const float* __restrict__ v,
                                        const int*   __restrict__ batch,
                                        float*       __restrict__ out) {
    __shared__ unsigned int hist[R * 32];        // 16 KiB: [bin][sub(2)][tl(16)]
    __shared__ unsigned int partial[64 * TT];    // 4 KiB:  [seg(64)][tl]
    __shared__ unsigned int sum8[8 * TT];        // 512 B:  [group(8)][tl]
    __shared__ int s_range[2];

    const int tid    = threadIdx.x;
    const int tg     = tid & (TG - 1);           // theta-group 0..3
    const int pl     = tid >> 2;                 // chunk-lane 0..255
    const int bat    = blockIdx.x / SPLIT_T;
    const int theta0 = (blockIdx.x % SPLIT_T) * TT;
    const int sub16  = ((pl >> 2) & 1) << 4;     // sub-histogram select (16-word offset)

    for (int i = tid; i < R * 32; i += NTHREADS) hist[i] = 0u;

    // ---- 64-ary cooperative lower_bound (3 dependent probe rounds).
    // wave 0 -> start, wave 1 -> end.
    const int wave = tid >> 6, lane = tid & 63;
    if (wave < 2) {
        const int val = bat + wave;
        int lo = 0, hi = N_PTS;
        while (lo < hi) {
            const int step = (hi - lo + 63) >> 6;
            const int pos  = lo + lane * step;
            const bool pred = (pos < hi) && (batch[pos] < val);
            const unsigned long long m = __ballot(pred);
            const int k = __popcll(m);
            if (k == 0) {
                hi = lo;
            } else {
                const int nlo = lo + (k - 1) * step + 1;
                hi = min(hi, lo + k * step);
                lo = nlo;
            }
        }
        if (lane == 0) s_range[wave] = lo;
    }

    // this thread's 4 thetas, diagonalized: tl_j = (4tg+j+pl) mod 16.
    // For fixed j the 4 lanes sharing tl have pl = {r, r-4, r-8, r-12} mod 16,
    // whose (pl>>2)&1 alternate -> exactly 2 lanes per (sub,tl) bank. 2-way = free.
    // off_j = sub16 + tl_j precombined; atomic addr = (bin<<5) + off_j (1 VALU).
    int   offj[4];
    float vv0[4], vv1[4], vv2[4];
#pragma unroll
    for (int j = 0; j < 4; ++j) {
        const int tl = (4 * tg + j + pl) & (TT - 1);
        offj[j] = sub16 + tl;
        // pre-scale by 64 so bin_f = dot(p, v*64) + 64 directly
        vv0[j] = v[0 * T + theta0 + tl] * 64.0f;
        vv1[j] = v[1 * T + theta0 + tl] * 64.0f;
        vv2[j] = v[2 * T + theta0 + tl] * 64.0f;
    }

    __syncthreads();
    const int start = s_range[0];
    const int end   = s_range[1];

    // chunk-of-4 points, 16B-aligned float4 loads. Chunks may cover <=2 points
    // past `end` (next batch) -> predicated out.
    const int a0      = start & ~3;
    const int nchunks = (end - a0 + 3) >> 2;
    const float4* __restrict__ X4 = (const float4*)x;
    const int cbase = (a0 >> 2) * 3;

    auto process4 = [&](int pbase, float4 f0, float4 f1, float4 f2) {
        const float px[4] = {f0.x, f0.w, f1.z, f2.y};
        const float py[4] = {f0.y, f1.x, f1.w, f2.z};
        const float pz[4] = {f0.z, f1.y, f2.x, f2.w};
        if (pbase >= start && pbase + 3 < end) {
#pragma unroll
            for (int i = 0; i < 4; ++i) {
#pragma unroll
                for (int j = 0; j < 4; ++j) {
                    const float bf = fmaf(px[i], vv0[j], fmaf(py[i], vv1[j],
                                     fmaf(pz[i], vv2[j], 64.0f)));
                    int bin = (int)bf;                       // trunc==floor after clamp
                    bin = min(max(bin, 0), R - 1);
                    atomicAdd(&hist[(bin << 5) + offj[j]], 1u);  // exact 2-way banked
                }
            }
        } else {
#pragma unroll
            for (int i = 0; i < 4; ++i) {
                const int p = pbase + i;
                if (p >= start && p < end) {
#pragma unroll
                    for (int j = 0; j < 4; ++j) {
                        const float bf = fmaf(px[i], vv0[j], fmaf(py[i], vv1[j],
                                         fmaf(pz[i], vv2[j], 64.0f)));
                        int bin = (int)bf;
                        bin = min(max(bin, 0), R - 1);
                        atomicAdd(&hist[(bin << 5) + offj[j]], 1u);
                    }
                }
            }
        }
    };

    // single chunk in flight (VGPR budget); 32 waves/CU provide the TLP to hide latency
    for (int c = pl; c < nchunks; c += PL) {
        const float4 f0 = X4[cbase + 3 * c];
        const float4 f1 = X4[cbase + 3 * c + 1];
        const float4 f2 = X4[cbase + 3 * c + 2];
        process4(a0 + 4 * c, f0, f1, f2);
    }

    __syncthreads();

    // cumsum over r. seg owns 2 rows; two-level (8x8) scan over the 64 segs.
    const int tl  = tid & (TT - 1);
    const int seg = tid >> 4;                 // 0..63
    const int r0  = seg * 2;
    unsigned int csum = 0;
#pragma unroll
    for (int r = r0; r < r0 + 2; ++r)
        csum += hist[(r << 5) + tl] + hist[(r << 5) + 16 + tl];
    partial[seg * TT + tl] = csum;
    __syncthreads();

    if (tid < 8 * TT) {                        // 8 groups x 16 tl
        const int g = tid >> 4;
        unsigned int s = 0;
#pragma unroll
        for (int k = 0; k < 8; ++k) s += partial[(g * 8 + k) * TT + tl];
        sum8[g * TT + tl] = s;
    }
    __syncthreads();

    unsigned int run = 0;
    const int g = seg >> 3;
    for (int gg = 0; gg < g; ++gg)        run += sum8[gg * TT + tl];
    for (int s2 = g * 8; s2 < seg; ++s2)  run += partial[s2 * TT + tl];
#pragma unroll
    for (int r = r0; r < r0 + 2; ++r) {
        run += hist[(r << 5) + tl] + hist[(r << 5) + 16 + tl];
        out[((size_t)bat * R + r) * T + theta0 + tl] = (float)run;  // exact in f32
    }
}

extern "C" void kernel_launch(void* const* d_in, const int* in_sizes, int n_in,
                              void* d_out, int out_size, void* d_ws, size_t ws_size,
                              hipStream_t stream) {
    const float* x     = (const float*)d_in[0];
    const float* v     = (const float*)d_in[1];
    const int*   batch = (const int*)d_in[2];
    float*       out   = (float*)d_out;

    dim3 grid(B * SPLIT_T);   // 512 blocks -> 2 per CU (VGPR-capped to fit)
    dim3 block(NTHREADS);
    hipLaunchKernelGGL(FastEctLayer_73065983639654_kernel, grid, block, 0, stream,
                       x, v, batch, out);
}

// Round 7
// 70.729 us; speedup vs baseline: 1.0259x; 1.0225x over previous
//
#include <hip/hip_runtime.h>

// ECT: nh = x @ v -> bin -> histogram over (batch, bin, theta) -> cumsum over bins.
// batch is SORTED: each block owns (batch, theta-slice) exclusively; no global
// atomics, no workspace.
//
// R1: 8x unroll (latency)                 42 -> ~26 us
// R2: 4 thetas/thread (VMEM issue)        ~26 -> ~21 us
// R3: float4 chunk loads + ballot search  ~21 -> ~16 us
// R4/R5: occupancy 2x + exact banking     NEUTRAL x2 -> occupancy theory dead.
// R6(this): DS-atomic scatter-roofline test. Invariant: 400K ds_add wave-instrs
//   (25.6M increments / 64), ~1562/CU; at ~15-20 cyc each -> 10-13 us floor.
//   This round reclaims the non-DS slop: search-first overlap, 3-deep
//   software-pipelined chunk loop, SPLIT_T=4 exact 2-way banking, VALU trim.
//   If neutral, the scatter roofline is established.

constexpr int N_PTS    = 200000;
constexpr int T        = 128;   // num_thetas
constexpr int R        = 128;   // resolution
constexpr int B        = 64;    // batch_size
constexpr int SPLIT_T  = 4;     // theta slices per batch
constexpr int TT       = T / SPLIT_T;       // 32 thetas per block
constexpr int NTHREADS = 1024;
constexpr int TG       = 8;                 // theta-groups per block (4 thetas each)
constexpr int PL       = NTHREADS / TG;     // 128 chunk-lanes per block
constexpr int SUBS     = NTHREADS / TT;     // 32 (epilogue segs)
constexpr int RCH      = R / SUBS;          // 4 rows per seg

__global__ __launch_bounds__(NTHREADS)
void FastEctLayer_73065983639654_kernel(const float* __restrict__ x,
                                        const float* __restrict__ v,
                                        const int*   __restrict__ batch,
                                        float*       __restrict__ out) {
    __shared__ unsigned int hist[R * TT];        // 16 KiB, [bin][tl]
    __shared__ unsigned int partial[SUBS * TT];  // 4 KiB, [seg][tl]
    __shared__ unsigned int grp[4 * TT];         // 512 B, [seg>>3][tl]
    __shared__ int s_range[2];

    const int tid  = threadIdx.x;
    const int wave = tid >> 6, lane = tid & 63;
    const int bat    = blockIdx.x >> 2;
    const int theta0 = (blockIdx.x & 3) * TT;

    // ---- search FIRST: waves 0/1 run the 3-round ballot lower_bound while
    // waves 2..15 proceed to hist init + v loads (overlapped).
    if (wave < 2) {
        const int val = bat + wave;
        int lo = 0, hi = N_PTS;
        while (lo < hi) {
            const int step = (hi - lo + 63) >> 6;
            const int pos  = lo + lane * step;
            const bool pred = (pos < hi) && (batch[pos] < val);
            const unsigned long long m = __ballot(pred);
            const int k = __popcll(m);
            if (k == 0) {
                hi = lo;
            } else {
                const int nlo = lo + (k - 1) * step + 1;
                hi = min(hi, lo + k * step);
                lo = nlo;
            }
        }
        if (lane == 0) s_range[wave] = lo;
    }

    for (int i = tid; i < R * TT; i += NTHREADS) hist[i] = 0u;

    // this thread's 4 thetas, diagonalized: tl_j = (4tg+j+pl) mod 32.
    // (tg,j)->4tg+j bijective over 0..31 (all thetas covered); for fixed j the
    // 64 lanes of a wave hit each bank exactly twice -> 2-way = free (m136).
    const int tg = tid & (TG - 1);               // 0..7
    const int pl = tid >> 3;                     // 0..127
    int   tlj[4];
    float vv0[4], vv1[4], vv2[4];
#pragma unroll
    for (int j = 0; j < 4; ++j) {
        const int tl = (4 * tg + j + pl) & (TT - 1);
        tlj[j] = tl;
        vv0[j] = v[0 * T + theta0 + tl] * 64.0f;   // pre-scaled: bin_f = dot + 64
        vv1[j] = v[1 * T + theta0 + tl] * 64.0f;
        vv2[j] = v[2 * T + theta0 + tl] * 64.0f;
    }

    __syncthreads();
    const int start = s_range[0];
    const int end   = s_range[1];

    // chunk-of-4 points, 16B-aligned float4 loads; <=2 points past `end`
    // predicated out (they belong to the next batch; end==N is 4-aligned w/ a0).
    const int a0      = start & ~3;
    const int nchunks = (end - a0 + 3) >> 2;
    const float4* __restrict__ X4 = (const float4*)x;
    const int cbase = (a0 >> 2) * 3;

    auto process4 = [&](int pbase, float4 f0, float4 f1, float4 f2) {
        const float px[4] = {f0.x, f0.w, f1.z, f2.y};
        const float py[4] = {f0.y, f1.x, f1.w, f2.z};
        const float pz[4] = {f0.z, f1.y, f2.x, f2.w};
        if (pbase >= start && pbase + 3 < end) {
#pragma unroll
            for (int i = 0; i < 4; ++i) {
#pragma unroll
                for (int j = 0; j < 4; ++j) {
                    const float bf = fmaf(px[i], vv0[j], fmaf(py[i], vv1[j],
                                     fmaf(pz[i], vv2[j], 64.0f)));
                    int bin = (int)bf;
                    bin = min(max(bin, 0), R - 1);      // v_med3_i32
                    atomicAdd(&hist[(bin << 5) + tlj[j]], 1u);  // ds_add, no return
                }
            }
        } else {
#pragma unroll
            for (int i = 0; i < 4; ++i) {
                const int p = pbase + i;
                if (p >= start && p < end) {
#pragma unroll
                    for (int j = 0; j < 4; ++j) {
                        const float bf = fmaf(px[i], vv0[j], fmaf(py[i], vv1[j],
                                         fmaf(pz[i], vv2[j], 64.0f)));
                        int bin = (int)bf;
                        bin = min(max(bin, 0), R - 1);
                        atomicAdd(&hist[(bin << 5) + tlj[j]], 1u);
                    }
                }
            }
        }
    };

    // ---- 3-deep software-pipelined chunk loop: loads for chunk c+2PL issued
    // before processing chunk c, so 1-2 chunks of VMEM stay in flight under
    // the VALU+DS burst. ~6 chunks/thread.
    int c = pl;
    float4 A0, A1, A2, B0, B1, B2;
    bool haveA = (c < nchunks);
    if (haveA) { A0 = X4[cbase + 3*c]; A1 = X4[cbase + 3*c + 1]; A2 = X4[cbase + 3*c + 2]; }
    bool haveB = (c + PL < nchunks);
    if (haveB) { B0 = X4[cbase + 3*(c+PL)]; B1 = X4[cbase + 3*(c+PL) + 1]; B2 = X4[cbase + 3*(c+PL) + 2]; }
    while (haveA) {
        const int cn = c + 2 * PL;
        const bool haveC = (cn < nchunks);
        float4 C0, C1, C2;
        if (haveC) { C0 = X4[cbase + 3*cn]; C1 = X4[cbase + 3*cn + 1]; C2 = X4[cbase + 3*cn + 2]; }
        process4(a0 + 4 * c, A0, A1, A2);
        A0 = B0; A1 = B1; A2 = B2; haveA = haveB;
        B0 = C0; B1 = C1; B2 = C2; haveB = haveC;
        c += PL;
    }

    __syncthreads();

    // cumsum over r: seg owns RCH=4 rows; two-level (4x8) scan over 32 segs.
    const int tl  = tid & (TT - 1);
    const int seg = tid >> 5;                 // 0..31
    const int r0  = seg * RCH;
    unsigned int csum = 0;
#pragma unroll
    for (int r = r0; r < r0 + RCH; ++r) csum += hist[(r << 5) + tl];
    partial[seg * TT + tl] = csum;
    __syncthreads();

    if (tid < 4 * TT) {                        // 4 groups x 32 tl
        const int g = tid >> 5;
        unsigned int s = 0;
#pragma unroll
        for (int k = 0; k < 8; ++k) s += partial[(g * 8 + k) * TT + tl];
        grp[g * TT + tl] = s;
    }
    __syncthreads();

    unsigned int run = 0;
    const int g = seg >> 3;
    for (int gg = 0; gg < g; ++gg)        run += grp[gg * TT + tl];      // <=3 broadcast reads
    for (int s2 = g * 8; s2 < seg; ++s2)  run += partial[s2 * TT + tl];  // <=7 broadcast reads
#pragma unroll
    for (int r = r0; r < r0 + RCH; ++r) {
        run += hist[(r << 5) + tl];
        out[((size_t)bat * R + r) * T + theta0 + tl] = (float)run;  // exact in f32
    }
}

extern "C" void kernel_launch(void* const* d_in, const int* in_sizes, int n_in,
                              void* d_out, int out_size, void* d_ws, size_t ws_size,
                              hipStream_t stream) {
    const float* x     = (const float*)d_in[0];
    const float* v     = (const float*)d_in[1];
    const int*   batch = (const int*)d_in[2];
    float*       out   = (float*)d_out;

    dim3 grid(B * SPLIT_T);   // 256 blocks = 1 per CU, 16 waves/CU
    dim3 block(NTHREADS);
    hipLaunchKernelGGL(FastEctLayer_73065983639654_kernel, grid, block, 0, stream,
                       x, v, batch, out);
}

// Round 8
// 70.545 us; speedup vs baseline: 1.0286x; 1.0026x over previous
//
#include <hip/hip_runtime.h>

// ECT: nh = x @ v -> bin -> histogram over (batch, bin, theta) -> cumsum over bins.
// batch is SORTED: each block owns (batch, theta-slice) exclusively; no global
// atomics, no workspace.
//
// R1: 8x unroll (latency)                 42 -> ~26 us
// R2: 4 thetas/thread (VMEM issue)        ~26 -> ~21 us
// R3: float4 chunk loads + ballot search  ~21 -> ~16 us
// R4/R5: occupancy 2x + exact banking     NEUTRAL x2 -> not occupancy-bound.
// R6: search-first + 3-deep pipeline      ~16 -> ~15 us.
// R7(this): structural floor = DS-atomic scatter: 400K ds_add wave-instrs
//   (25.6M/64, invariant) x ~17-19 cyc ≈ 11-13 us. This round trims the last
//   non-DS slop: (a) XCD swizzle - siblings (same bat, 4 theta-slices) now map
//   to the SAME XCD (bat = bIdx&63: siblings differ by 64 ≡ 0 mod 8) so x is
//   fetched into 1 L2 not 4 (FETCH 14.5 -> ~6 MB); (b) hist init owned by
//   waves 2..15 as uint4 writes, off the search critical path.
//   If neutral: scatter roofline established.

constexpr int N_PTS    = 200000;
constexpr int T        = 128;   // num_thetas
constexpr int R        = 128;   // resolution
constexpr int B        = 64;    // batch_size
constexpr int TT       = 32;    // thetas per block (4 slices per batch)
constexpr int NTHREADS = 1024;
constexpr int TG       = 8;     // theta-groups per block (4 thetas each)
constexpr int PL       = NTHREADS / TG;     // 128 chunk-lanes per block
constexpr int SUBS     = NTHREADS / TT;     // 32 epilogue segs
constexpr int RCH      = R / SUBS;          // 4 rows per seg

__global__ __launch_bounds__(NTHREADS)
void FastEctLayer_73065983639654_kernel(const float* __restrict__ x,
                                        const float* __restrict__ v,
                                        const int*   __restrict__ batch,
                                        float*       __restrict__ out) {
    __shared__ uint4        hist4[R * TT / 4];   // 16 KiB, [bin][tl] as u32
    __shared__ unsigned int partial[SUBS * TT];  // 4 KiB, [seg][tl]
    __shared__ unsigned int grp[4 * TT];         // 512 B
    __shared__ int s_range[2];
    unsigned int* hist = (unsigned int*)hist4;

    const int tid  = threadIdx.x;
    const int wave = tid >> 6, lane = tid & 63;
    // XCD swizzle: the 4 sibling blocks of a batch (slices 0..3) have blockIdx
    // = bat, bat+64, bat+128, bat+192 -> all equal mod 8 -> same XCD L2.
    const int bat    = blockIdx.x & 63;
    const int theta0 = (blockIdx.x >> 6) * TT;

    if (wave < 2) {
        // ---- 64-ary cooperative lower_bound (3 dependent probe rounds).
        // wave 0 -> start, wave 1 -> end. Runs under waves 2..15's init.
        const int val = bat + wave;
        int lo = 0, hi = N_PTS;
        while (lo < hi) {
            const int step = (hi - lo + 63) >> 6;
            const int pos  = lo + lane * step;
            const bool pred = (pos < hi) && (batch[pos] < val);
            const unsigned long long m = __ballot(pred);
            const int k = __popcll(m);
            if (k == 0) {
                hi = lo;
            } else {
                const int nlo = lo + (k - 1) * step + 1;
                hi = min(hi, lo + k * step);
                lo = nlo;
            }
        }
        if (lane == 0) s_range[wave] = lo;
    } else {
        // waves 2..15 own the full hist init (vectorized, off the critical path)
        const uint4 z = {0u, 0u, 0u, 0u};
        for (int i = tid - 128; i < R * TT / 4; i += NTHREADS - 128) hist4[i] = z;
    }

    // this thread's 4 thetas, diagonalized: tl_j = (4tg+j+pl) mod 32.
    // (tg,j)->4tg+j bijective (all 32 thetas covered); for fixed j a wave hits
    // each bank exactly twice -> 2-way = free (m136).
    const int tg = tid & (TG - 1);               // 0..7
    const int pl = tid >> 3;                     // 0..127
    int   tlj[4];
    float vv0[4], vv1[4], vv2[4];
#pragma unroll
    for (int j = 0; j < 4; ++j) {
        const int tl = (4 * tg + j + pl) & (TT - 1);
        tlj[j] = tl;
        vv0[j] = v[0 * T + theta0 + tl] * 64.0f;   // pre-scaled: bin_f = dot + 64
        vv1[j] = v[1 * T + theta0 + tl] * 64.0f;
        vv2[j] = v[2 * T + theta0 + tl] * 64.0f;
    }

    __syncthreads();
    const int start = s_range[0];
    const int end   = s_range[1];

    // chunk-of-4 points, 16B-aligned float4 loads; <=2 points past `end`
    // predicated out (next batch's points; end==N is 4-aligned with a0).
    const int a0      = start & ~3;
    const int nchunks = (end - a0 + 3) >> 2;
    const float4* __restrict__ X4 = (const float4*)x;
    const int cbase = (a0 >> 2) * 3;

    auto process4 = [&](int pbase, float4 f0, float4 f1, float4 f2) {
        const float px[4] = {f0.x, f0.w, f1.z, f2.y};
        const float py[4] = {f0.y, f1.x, f1.w, f2.z};
        const float pz[4] = {f0.z, f1.y, f2.x, f2.w};
        if (pbase >= start && pbase + 3 < end) {
#pragma unroll
            for (int i = 0; i < 4; ++i) {
#pragma unroll
                for (int j = 0; j < 4; ++j) {
                    const float bf = fmaf(px[i], vv0[j], fmaf(py[i], vv1[j],
                                     fmaf(pz[i], vv2[j], 64.0f)));
                    int bin = (int)bf;
                    bin = min(max(bin, 0), R - 1);          // v_med3_i32
                    atomicAdd(&hist[(bin << 5) + tlj[j]], 1u);  // ds_add, no return
                }
            }
        } else {
#pragma unroll
            for (int i = 0; i < 4; ++i) {
                const int p = pbase + i;
                if (p >= start && p < end) {
#pragma unroll
                    for (int j = 0; j < 4; ++j) {
                        const float bf = fmaf(px[i], vv0[j], fmaf(py[i], vv1[j],
                                         fmaf(pz[i], vv2[j], 64.0f)));
                        int bin = (int)bf;
                        bin = min(max(bin, 0), R - 1);
                        atomicAdd(&hist[(bin << 5) + tlj[j]], 1u);
                    }
                }
            }
        }
    };

    // 3-deep software-pipelined chunk loop: loads for chunk c+2PL issued before
    // processing chunk c -> 1-2 chunks of VMEM in flight under the VALU+DS burst.
    int c = pl;
    float4 A0, A1, A2, B0, B1, B2;
    bool haveA = (c < nchunks);
    if (haveA) { A0 = X4[cbase + 3*c]; A1 = X4[cbase + 3*c + 1]; A2 = X4[cbase + 3*c + 2]; }
    bool haveB = (c + PL < nchunks);
    if (haveB) { B0 = X4[cbase + 3*(c+PL)]; B1 = X4[cbase + 3*(c+PL) + 1]; B2 = X4[cbase + 3*(c+PL) + 2]; }
    while (haveA) {
        const int cn = c + 2 * PL;
        const bool haveC = (cn < nchunks);
        float4 C0, C1, C2;
        if (haveC) { C0 = X4[cbase + 3*cn]; C1 = X4[cbase + 3*cn + 1]; C2 = X4[cbase + 3*cn + 2]; }
        process4(a0 + 4 * c, A0, A1, A2);
        A0 = B0; A1 = B1; A2 = B2; haveA = haveB;
        B0 = C0; B1 = C1; B2 = C2; haveB = haveC;
        c += PL;
    }

    __syncthreads();

    // cumsum over r: seg owns RCH=4 rows; two-level (4x8) scan over 32 segs.
    const int tl  = tid & (TT - 1);
    const int seg = tid >> 5;                 // 0..31
    const int r0  = seg * RCH;
    unsigned int csum = 0;
#pragma unroll
    for (int r = r0; r < r0 + RCH; ++r) csum += hist[(r << 5) + tl];
    partial[seg * TT + tl] = csum;
    __syncthreads();

    if (tid < 4 * TT) {                        // 4 groups x 32 tl
        const int g = tid >> 5;
        unsigned int s = 0;
#pragma unroll
        for (int k = 0; k < 8; ++k) s += partial[(g * 8 + k) * TT + tl];
        grp[g * TT + tl] = s;
    }
    __syncthreads();

    unsigned int run = 0;
    const int g = seg >> 3;
    for (int gg = 0; gg < g; ++gg)        run += grp[gg * TT + tl];      // <=3 broadcast reads
    for (int s2 = g * 8; s2 < seg; ++s2)  run += partial[s2 * TT + tl];  // <=7 broadcast reads
#pragma unroll
    for (int r = r0; r < r0 + RCH; ++r) {
        run += hist[(r << 5) + tl];
        out[((size_t)bat * R + r) * T + theta0 + tl] = (float)run;  // exact in f32
    }
}

extern "C" void kernel_launch(void* const* d_in, const int* in_sizes, int n_in,
                              void* d_out, int out_size, void* d_ws, size_t ws_size,
                              hipStream_t stream) {
    const float* x     = (const float*)d_in[0];
    const float* v     = (const float*)d_in[1];
    const int*   batch = (const int*)d_in[2];
    float*       out   = (float*)d_out;

    dim3 grid(B * 4);   // 256 blocks = 1 per CU; bat = bIdx&63 (XCD-swizzled)
    dim3 block(NTHREADS);
    hipLaunchKernelGGL(FastEctLayer_73065983639654_kernel, grid, block, 0, stream,
                       x, v, batch, out);
}